// Round 7
// baseline (2625.598 us; speedup 1.0000x reference)
//
#include <hip/hip_runtime.h>
#include <hip/hip_bf16.h>
#include <stdint.h>

typedef __hip_bfloat16 bf16;
typedef __attribute__((ext_vector_type(8))) short bf16x8s;   // MFMA A/B fragment (8 bf16)
typedef __attribute__((ext_vector_type(4))) float f32x4;     // MFMA accumulator
typedef __attribute__((ext_vector_type(8))) unsigned short us8;

#define DEV __device__ __forceinline__

// ---- problem dims ----
static constexpr int Bn = 2, Ln = 2048, Hn = 2048, DINn = 4096, DSn = 128;
static constexpr int NHn = 64, FFn = 8192;
static constexpr int CONVD = DINn + 2 * DSn;            // 4352
static constexpr int DPROJ = 2 * DINn + 2 * DSn + NHn;  // 8512
static constexpr int DPROJP = 8576;                     // padded to 128 multiple (for GEMM grid)
static constexpr int BL = Bn * Ln;                      // 4096
static constexpr int TCH = 16, LC = Ln / TCH;           // chunked scan: 16 chunks x 128 steps

DEV float bf2f(unsigned short x) {
  union { unsigned int u; float f; } v; v.u = ((unsigned int)x) << 16; return v.f;
}
DEV float bfload(const bf16* p) { return bf2f(*(const unsigned short*)p); }
DEV float sigmoidf_(float x) { return 1.f / (1.f + __expf(-x)); }

// ---------------- transpose fp32 [K][N] -> bf16 [N][K] ----------------
__global__ __launch_bounds__(256) void transpose_f2b_k(
    const float* __restrict__ in, bf16* __restrict__ out, int K, int N) {
  __shared__ bf16 t[32][33];
  int nb = blockIdx.x * 32, kb = blockIdx.y * 32;
  int tx = threadIdx.x & 31, ty = threadIdx.x >> 5;
#pragma unroll
  for (int r = 0; r < 32; r += 8)
    t[ty + r][tx] = __float2bfloat16(in[(size_t)(kb + ty + r) * N + nb + tx]);
  __syncthreads();
#pragma unroll
  for (int r = 0; r < 32; r += 8)
    out[(size_t)(nb + ty + r) * K + kb + tx] = t[tx][ty + r];
}

// ---------------- rmsnorm, fp32 in -> bf16 out (row = 2048) ----------------
__global__ __launch_bounds__(256) void rmsnorm_f32_k(
    const float* __restrict__ in, const float* __restrict__ g, bf16* __restrict__ out) {
  int row = blockIdx.x, tid = threadIdx.x;
  const float* rp = in + (size_t)row * Hn + tid * 8;
  float4 a = *(const float4*)rp;
  float4 b = *(const float4*)(rp + 4);
  float v[8] = {a.x, a.y, a.z, a.w, b.x, b.y, b.z, b.w};
  float ss = 0.f;
#pragma unroll
  for (int j = 0; j < 8; ++j) ss += v[j] * v[j];
#pragma unroll
  for (int o = 1; o < 64; o <<= 1) ss += __shfl_xor(ss, o, 64);
  __shared__ float red[4];
  if ((tid & 63) == 0) red[tid >> 6] = ss;
  __syncthreads();
  float sc = rsqrtf((red[0] + red[1] + red[2] + red[3]) / Hn + 1e-5f);
  float4 g0 = *(const float4*)(g + tid * 8);
  float4 g1 = *(const float4*)(g + tid * 8 + 4);
  float gv[8] = {g0.x, g0.y, g0.z, g0.w, g1.x, g1.y, g1.z, g1.w};
  us8 ov;
#pragma unroll
  for (int j = 0; j < 8; ++j)
    ((bf16*)&ov)[j] = __float2bfloat16(v[j] * sc * gv[j]);
  *(us8*)(out + (size_t)row * Hn + tid * 8) = ov;
}

// ---------------- MFMA GEMM: C[M][N] = A[M][lda] (bf16) @ Bt[Np][K]^T (bf16) ----------------
// 128x128 tile, BK=64, 4 waves (2x2), 16x16x32 bf16 MFMA, global_load_lds staging.
// OutT: float or bf16. EPI 1: adds fp32 Res[M][N]. Stores guarded by col<N.
template<int EPI, typename OutT>
__global__ __launch_bounds__(256) void gemm_k(
    const bf16* __restrict__ A, const bf16* __restrict__ Bt,
    OutT* __restrict__ C, const float* __restrict__ Res,
    int K, int lda, int N) {
  __shared__ bf16 As[128 * 64];
  __shared__ bf16 Bs[128 * 64];
  int m0 = blockIdx.y * 128, n0 = blockIdx.x * 128;
  int tid = threadIdx.x;
  int lane = tid & 63;
  int wid = tid >> 6;
  int wr = wid >> 1, wc = wid & 1;
  f32x4 acc[4][4] = {};
  int srow = tid >> 3;
  int scol = (tid & 7) * 8;
  const bf16* Ag = A + (size_t)(m0 + srow) * lda + scol;
  const bf16* Bg = Bt + (size_t)(n0 + srow) * K + scol;
  char* AsB = (char*)As;
  char* BsB = (char*)Bs;
  for (int k0 = 0; k0 < K; k0 += 64) {
#pragma unroll
    for (int i = 0; i < 4; ++i)
      __builtin_amdgcn_global_load_lds(
          (const __attribute__((address_space(1))) unsigned int*)(Ag + (size_t)i * 32 * lda + k0),
          (__attribute__((address_space(3))) unsigned int*)(AsB + i * 4096 + tid * 16),
          16, 0, 0);
#pragma unroll
    for (int i = 0; i < 4; ++i)
      __builtin_amdgcn_global_load_lds(
          (const __attribute__((address_space(1))) unsigned int*)(Bg + (size_t)i * 32 * K + k0),
          (__attribute__((address_space(3))) unsigned int*)(BsB + i * 4096 + tid * 16),
          16, 0, 0);
    __syncthreads();
#pragma unroll
    for (int kk = 0; kk < 2; ++kk) {
      int krow = kk * 32 + (lane >> 4) * 8;
      bf16x8s af[4], bfv[4];
#pragma unroll
      for (int m = 0; m < 4; ++m)
        af[m] = *(const bf16x8s*)(As + (wr * 64 + m * 16 + (lane & 15)) * 64 + krow);
#pragma unroll
      for (int n = 0; n < 4; ++n)
        bfv[n] = *(const bf16x8s*)(Bs + (wc * 64 + n * 16 + (lane & 15)) * 64 + krow);
#pragma unroll
      for (int m = 0; m < 4; ++m)
#pragma unroll
        for (int n = 0; n < 4; ++n)
          acc[m][n] = __builtin_amdgcn_mfma_f32_16x16x32_bf16(af[m], bfv[n], acc[m][n], 0, 0, 0);
    }
    __syncthreads();
  }
#pragma unroll
  for (int m = 0; m < 4; ++m) {
#pragma unroll
    for (int n = 0; n < 4; ++n) {
      int col = n0 + wc * 64 + n * 16 + (lane & 15);
      if (col < N) {
#pragma unroll
        for (int r = 0; r < 4; ++r) {
          int row = m0 + wr * 64 + m * 16 + (lane >> 4) * 4 + r;
          float vv = acc[m][n][r];
          if (EPI == 1) vv += Res[(size_t)row * N + col];
          if constexpr (__is_same(OutT, float)) C[(size_t)row * N + col] = vv;
          else C[(size_t)row * N + col] = __float2bfloat16(vv);
        }
      }
    }
  }
}

// ---------------- depthwise causal conv (DCONV=4) + bias + silu ----------------
__global__ __launch_bounds__(256) void conv_silu_k(
    const bf16* __restrict__ proj, const float* __restrict__ cw,
    const float* __restrict__ cb, bf16* __restrict__ xb, float* __restrict__ bc) {
  int c = blockIdx.x * 256 + threadIdx.x;   // < CONVD
  int bt = blockIdx.y;
  int l = bt & (Ln - 1);
  const bf16* base = proj + (size_t)bt * DPROJ + DINn + c;
  float acc = cb[c];
#pragma unroll
  for (int k = 0; k < 4; ++k) {
    int dl = l - 3 + k;
    if (dl >= 0) acc += bfload(base + (ptrdiff_t)(k - 3) * DPROJ) * cw[c * 4 + k];
  }
  float r = acc * sigmoidf_(acc);
  if (c < DINn) xb[(size_t)bt * DINn + c] = __float2bfloat16(r);
  else          bc[(size_t)bt * 256 + (c - DINn)] = r;
}

// ---------------- dt = softplus(raw + bias), dA = exp(dt * -exp(A_log)) ----------------
__global__ __launch_bounds__(256) void dtda_k(
    const bf16* __restrict__ proj, const float* __restrict__ dt_bias,
    const float* __restrict__ A_log, float* __restrict__ dt, float* __restrict__ da) {
  int i = blockIdx.x * 256 + threadIdx.x;   // BL*NH
  int bt = i >> 6, h = i & 63;
  float raw = bfload(proj + (size_t)bt * DPROJ + (DINn + CONVD) + h) + dt_bias[h];
  float dtv = raw > 20.f ? raw : log1pf(expf(raw));
  float Ah = -expf(A_log[h]);
  dt[i] = dtv;
  da[i] = expf(dtv * Ah);
}

// ---------------- chunked selective scan, K1: local scan per chunk ----------------
// grid 4096 = (b, h, ph, ch). Thread (pl, sq): p = ph*32+pl, states [sq*16, sq*16+16).
// Zero-init local scan over LC=128 steps; writes y_local (bf16, incl. D*x), h_end (fp32),
// and cumA_t (running per-head dA product within chunk; thread 0 of ph==0 blocks).
__global__ __launch_bounds__(256) void scan_chunk_k(
    const bf16* __restrict__ xb, const float* __restrict__ bc,
    const float* __restrict__ dtb, const float* __restrict__ dab,
    const float* __restrict__ Dp, bf16* __restrict__ ys,
    float* __restrict__ hend, float* __restrict__ cuma) {
  int idx = blockIdx.x;
  int ch = idx & (TCH - 1);
  int ph = (idx >> 4) & 1;
  int h  = (idx >> 5) & 63;
  int b  = idx >> 11;
  int tid = threadIdx.x;
  int pl = tid >> 3, sq = tid & 7;
  int p = ph * 32 + pl;
  size_t row0 = (size_t)b * Ln + ch * LC;
  const bf16*  xp  = xb  + row0 * DINn + h * 64 + p;
  const float* Bp  = bc  + row0 * 256 + sq * 16;
  const float* Cp  = Bp + DSn;
  const float* dtp = dtb + row0 * NHn + h;
  const float* dap = dab + row0 * NHn + h;
  bf16* yp = ys + row0 * DINn + h * 64 + p;
  float* cap = cuma + row0 * NHn + h;
  float Dh = Dp[h];
  float st[16];
#pragma unroll
  for (int j = 0; j < 16; ++j) st[j] = 0.f;
  float ca = 1.f;
  bool wca = (tid == 0) && (ph == 0);
  float4 B0 = *(const float4*)(Bp),     B1 = *(const float4*)(Bp + 4);
  float4 B2 = *(const float4*)(Bp + 8), B3 = *(const float4*)(Bp + 12);
  float4 C0 = *(const float4*)(Cp),     C1 = *(const float4*)(Cp + 4);
  float4 C2 = *(const float4*)(Cp + 8), C3 = *(const float4*)(Cp + 12);
  float xc = bfload(xp), dac = *dap, dtc = *dtp;
  for (int t = 0; t < LC; ++t) {
    int tn = (t + 1 < LC) ? t + 1 : t;
    const float* bb = Bp + (size_t)tn * 256;
    const float* cc = Cp + (size_t)tn * 256;
    float4 nB0 = *(const float4*)(bb),     nB1 = *(const float4*)(bb + 4);
    float4 nB2 = *(const float4*)(bb + 8), nB3 = *(const float4*)(bb + 12);
    float4 nC0 = *(const float4*)(cc),     nC1 = *(const float4*)(cc + 4);
    float4 nC2 = *(const float4*)(cc + 8), nC3 = *(const float4*)(cc + 12);
    float nx  = bfload(xp + (size_t)tn * DINn);
    float nda = dap[(size_t)tn * NHn];
    float ndt = dtp[(size_t)tn * NHn];

    float u = dtc * xc;
    float y0 = 0.f, y1 = 0.f, y2 = 0.f, y3 = 0.f;
#define SSTEP(i, acc, Bv, Cv) \
    st[i] = fmaf(st[i], dac, u * (Bv)); acc = fmaf(st[i], (Cv), acc);
    SSTEP(0,  y0, B0.x, C0.x)  SSTEP(1,  y1, B0.y, C0.y)
    SSTEP(2,  y2, B0.z, C0.z)  SSTEP(3,  y3, B0.w, C0.w)
    SSTEP(4,  y0, B1.x, C1.x)  SSTEP(5,  y1, B1.y, C1.y)
    SSTEP(6,  y2, B1.z, C1.z)  SSTEP(7,  y3, B1.w, C1.w)
    SSTEP(8,  y0, B2.x, C2.x)  SSTEP(9,  y1, B2.y, C2.y)
    SSTEP(10, y2, B2.z, C2.z)  SSTEP(11, y3, B2.w, C2.w)
    SSTEP(12, y0, B3.x, C3.x)  SSTEP(13, y1, B3.y, C3.y)
    SSTEP(14, y2, B3.z, C3.z)  SSTEP(15, y3, B3.w, C3.w)
#undef SSTEP
    ca *= dac;
    if (wca) cap[(size_t)t * NHn] = ca;
    float ysum = (y0 + y1) + (y2 + y3);
    ysum += __shfl_xor(ysum, 1, 64);
    ysum += __shfl_xor(ysum, 2, 64);
    ysum += __shfl_xor(ysum, 4, 64);
    if (sq == 0) yp[(size_t)t * DINn] = __float2bfloat16(fmaf(Dh, xc, ysum));
    B0 = nB0; B1 = nB1; B2 = nB2; B3 = nB3;
    C0 = nC0; C1 = nC1; C2 = nC2; C3 = nC3;
    xc = nx; dac = nda; dtc = ndt;
  }
  // write chunk-final local state
  float* he = hend + ((((size_t)(b * NHn + h) * TCH + ch) * 64 + p) * 128) + sq * 16;
  *(float4*)(he)      = make_float4(st[0],  st[1],  st[2],  st[3]);
  *(float4*)(he + 4)  = make_float4(st[4],  st[5],  st[6],  st[7]);
  *(float4*)(he + 8)  = make_float4(st[8],  st[9],  st[10], st[11]);
  *(float4*)(he + 12) = make_float4(st[12], st[13], st[14], st[15]);
}

// ---------------- K2: carry propagation, in-place h_end -> h_init ----------------
// grid 128 = (b,h); each thread owns 32 contiguous floats of the 8192-elem state.
__global__ __launch_bounds__(256) void carry_k(
    float* __restrict__ hend, const float* __restrict__ cuma) {
  int blk = blockIdx.x;
  int b = blk >> 6, h = blk & 63;
  int tid = threadIdx.x;
  float* base = hend + (size_t)blk * TCH * 8192 + tid * 32;
  float c[32];
#pragma unroll
  for (int i = 0; i < 32; ++i) c[i] = 0.f;
  for (int j = 0; j < TCH; ++j) {
    float aT = cuma[((size_t)b * Ln + j * LC + LC - 1) * NHn + h];
    float* pj = base + (size_t)j * 8192;
    float tmp[32];
#pragma unroll
    for (int q = 0; q < 8; ++q) {
      float4 v = ((const float4*)pj)[q];
      tmp[q * 4 + 0] = v.x; tmp[q * 4 + 1] = v.y; tmp[q * 4 + 2] = v.z; tmp[q * 4 + 3] = v.w;
    }
#pragma unroll
    for (int q = 0; q < 8; ++q)
      ((float4*)pj)[q] = make_float4(c[q * 4], c[q * 4 + 1], c[q * 4 + 2], c[q * 4 + 3]);
#pragma unroll
    for (int i = 0; i < 32; ++i) c[i] = fmaf(aT, c[i], tmp[i]);
  }
}

// ---------------- K3: correction y += cumA_t * (C_t . h_init) ----------------
// same grid/thread layout as K1.
__global__ __launch_bounds__(256) void scancorr_k(
    const float* __restrict__ bc, const float* __restrict__ cuma,
    const float* __restrict__ hinit, bf16* __restrict__ ys) {
  int idx = blockIdx.x;
  int ch = idx & (TCH - 1);
  int ph = (idx >> 4) & 1;
  int h  = (idx >> 5) & 63;
  int b  = idx >> 11;
  int tid = threadIdx.x;
  int pl = tid >> 3, sq = tid & 7;
  int p = ph * 32 + pl;
  size_t row0 = (size_t)b * Ln + ch * LC;
  const float* hi = hinit + ((((size_t)(b * NHn + h) * TCH + ch) * 64 + p) * 128) + sq * 16;
  float h0[16];
#pragma unroll
  for (int q = 0; q < 4; ++q) {
    float4 v = ((const float4*)hi)[q];
    h0[q * 4 + 0] = v.x; h0[q * 4 + 1] = v.y; h0[q * 4 + 2] = v.z; h0[q * 4 + 3] = v.w;
  }
  const float* Cp  = bc + row0 * 256 + DSn + sq * 16;
  const float* cap = cuma + row0 * NHn + h;
  bf16* yp = ys + row0 * DINn + h * 64 + p;
#pragma unroll 2
  for (int t = 0; t < LC; ++t) {
    const float* cc = Cp + (size_t)t * 256;
    float4 Cv0 = *(const float4*)(cc),     Cv1 = *(const float4*)(cc + 4);
    float4 Cv2 = *(const float4*)(cc + 8), Cv3 = *(const float4*)(cc + 12);
    float d = 0.f;
    d = fmaf(h0[0],  Cv0.x, d); d = fmaf(h0[1],  Cv0.y, d);
    d = fmaf(h0[2],  Cv0.z, d); d = fmaf(h0[3],  Cv0.w, d);
    d = fmaf(h0[4],  Cv1.x, d); d = fmaf(h0[5],  Cv1.y, d);
    d = fmaf(h0[6],  Cv1.z, d); d = fmaf(h0[7],  Cv1.w, d);
    d = fmaf(h0[8],  Cv2.x, d); d = fmaf(h0[9],  Cv2.y, d);
    d = fmaf(h0[10], Cv2.z, d); d = fmaf(h0[11], Cv2.w, d);
    d = fmaf(h0[12], Cv3.x, d); d = fmaf(h0[13], Cv3.y, d);
    d = fmaf(h0[14], Cv3.z, d); d = fmaf(h0[15], Cv3.w, d);
    d += __shfl_xor(d, 1, 64);
    d += __shfl_xor(d, 2, 64);
    d += __shfl_xor(d, 4, 64);
    if (sq == 0) {
      float ca = cap[(size_t)t * NHn];
      bf16* yy = yp + (size_t)t * DINn;
      *yy = __float2bfloat16(fmaf(ca, d, bfload(yy)));
    }
  }
}

// ---------------- gated rmsnorm: out = rmsnorm(y * silu(z)) * w  (row = 4096) ----------------
__global__ __launch_bounds__(256) void gated_norm_k(
    const bf16* __restrict__ ys, const bf16* __restrict__ proj,
    const float* __restrict__ gw, bf16* __restrict__ out) {
  int row = blockIdx.x, tid = threadIdx.x;
  const bf16* yr = ys + (size_t)row * DINn;
  const bf16* zr = proj + (size_t)row * DPROJ;
  float v[2][8];
  float ss = 0.f;
#pragma unroll
  for (int it = 0; it < 2; ++it) {
    int base = (it * 256 + tid) * 8;
    us8 y = *(const us8*)(yr + base);
    us8 z = *(const us8*)(zr + base);
#pragma unroll
    for (int j = 0; j < 8; ++j) {
      float zf = bf2f(z[j]);
      float val = bf2f(y[j]) * zf * sigmoidf_(zf);
      v[it][j] = val; ss += val * val;
    }
  }
#pragma unroll
  for (int o = 1; o < 64; o <<= 1) ss += __shfl_xor(ss, o, 64);
  __shared__ float red[4];
  if ((tid & 63) == 0) red[tid >> 6] = ss;
  __syncthreads();
  float sc = rsqrtf((red[0] + red[1] + red[2] + red[3]) / DINn + 1e-5f);
#pragma unroll
  for (int it = 0; it < 2; ++it) {
    int base = (it * 256 + tid) * 8;
    float4 g0 = *(const float4*)(gw + base);
    float4 g1 = *(const float4*)(gw + base + 4);
    float gv[8] = {g0.x, g0.y, g0.z, g0.w, g1.x, g1.y, g1.z, g1.w};
    us8 ov;
#pragma unroll
    for (int j = 0; j < 8; ++j)
      ((bf16*)&ov)[j] = __float2bfloat16(v[it][j] * sc * gv[j]);
    *(us8*)(out + (size_t)row * DINn + base) = ov;
  }
}

// ---------------- swiglu act, IN-PLACE on gu ----------------
__global__ __launch_bounds__(256) void act_k(bf16* __restrict__ gu) {
  int i = blockIdx.x * 256 + threadIdx.x;
  int row = i >> 10, g = i & 1023;
  bf16* rp = gu + (size_t)row * (2 * FFn) + g * 8;
  us8 a = *(const us8*)(rp);
  us8 bx = *(const us8*)(rp + FFn);
  us8 ov;
#pragma unroll
  for (int j = 0; j < 8; ++j) {
    float av = bf2f(a[j]), bv = bf2f(bx[j]);
    ((bf16*)&ov)[j] = __float2bfloat16(av * sigmoidf_(av) * bv);
  }
  *(us8*)rp = ov;
}

// ---------------- launch ----------------
extern "C" void kernel_launch(void* const* d_in, const int* in_sizes, int n_in,
                              void* d_out, int out_size, void* d_ws, size_t ws_size,
                              hipStream_t stream) {
  (void)in_sizes; (void)n_in; (void)out_size; (void)ws_size;
  const float* hidden  = (const float*)d_in[0];
  const float* w_in    = (const float*)d_in[1];
  const float* conv_w  = (const float*)d_in[2];
  const float* conv_b  = (const float*)d_in[3];
  const float* A_log   = (const float*)d_in[4];
  const float* D_ssm   = (const float*)d_in[5];
  const float* dt_bias = (const float*)d_in[6];
  const float* norm_w  = (const float*)d_in[7];
  const float* w_out   = (const float*)d_in[8];
  const float* ln1_w   = (const float*)d_in[9];
  const float* ln2_w   = (const float*)d_in[10];
  const float* w_gu    = (const float*)d_in[11];
  const float* w_dn    = (const float*)d_in[12];

  // ---- workspace layout, 261.6 MiB peak, liveness-checked ----
  char* ws = (char*)d_ws;
  const size_t OFF_WT   = 0;                          // 67,108,864  weight-T buffer (max: w_guT)
  const size_t OFF_PROJ = 67108864ull;                // 69,730,304  proj bf16 [4096][8512]
  const size_t OFF_XB   = OFF_PROJ + 69730304ull;     // 33,554,432  conv x bf16 [4096][4096]
  const size_t OFF_BC   = OFF_XB  + 33554432ull;      //  4,194,304  conv B/C fp32 [4096][256]
  const size_t OFF_DTB  = OFF_BC  + 4194304ull;       //  1,048,576
  const size_t OFF_DAB  = OFF_DTB + 1048576ull;       //  1,048,576
  const size_t OFF_YS   = OFF_DAB + 1048576ull;       // 33,554,432  scan out bf16 [4096][4096]
  const size_t OFF_YBF  = OFF_YS  + 33554432ull;      // 33,554,432  gated-norm out bf16
  const size_t OFF_HLN  = OFF_YBF + 33554432ull;      // 16,777,216  ln out bf16 [4096][2048]
  const size_t OFF_CUMA = OFF_HLN + 16777216ull;      //  1,048,576  cumA fp32 [4096][64]
  // aliases (regions dead at write time):
  const size_t OFF_HEND = OFF_WT;                     // 67,108,864  EXACT: B*NH*TCH*64*128*4; wT dead between in_proj GEMM and out_proj transpose
  const size_t OFF_GU   = OFF_PROJ;                   // 134,217,728 gu bf16 [4096][16384] over proj..ys (dead after gated_norm)

  bf16*  wT   = (bf16*)(ws + OFF_WT);
  bf16*  proj = (bf16*)(ws + OFF_PROJ);
  bf16*  xb   = (bf16*)(ws + OFF_XB);
  float* bc   = (float*)(ws + OFF_BC);
  float* dtb  = (float*)(ws + OFF_DTB);
  float* dab  = (float*)(ws + OFF_DAB);
  bf16*  ysb  = (bf16*)(ws + OFF_YS);
  bf16*  ybf  = (bf16*)(ws + OFF_YBF);
  bf16*  hln  = (bf16*)(ws + OFF_HLN);
  float* cuma = (float*)(ws + OFF_CUMA);
  float* hend = (float*)(ws + OFF_HEND);
  bf16*  gu   = (bf16*)(ws + OFF_GU);

  float* h_out = (float*)d_out;                 // output 0: h  (fp32)
  float* resid = h_out + (size_t)BL * Hn;       // output 1: residual (fp32)

  // ---- mixer ----
  transpose_f2b_k<<<dim3(DPROJ / 32, Hn / 32), 256, 0, stream>>>(w_in, wT, Hn, DPROJ);
  hipMemsetAsync(wT + (size_t)DPROJ * Hn, 0, (size_t)(DPROJP - DPROJ) * Hn * 2, stream);
  rmsnorm_f32_k<<<BL, 256, 0, stream>>>(hidden, ln1_w, hln);
  gemm_k<0, bf16><<<dim3(DPROJP / 128, BL / 128), 256, 0, stream>>>(
      hln, wT, proj, nullptr, Hn, Hn, DPROJ);

  conv_silu_k<<<dim3(CONVD / 256, BL), 256, 0, stream>>>(proj, conv_w, conv_b, xb, bc);
  dtda_k<<<BL * NHn / 256, 256, 0, stream>>>(proj, dt_bias, A_log, dtb, dab);

  // chunked scan (hend aliases wT -- wT re-filled after gated_norm)
  scan_chunk_k<<<Bn * NHn * 2 * TCH, 256, 0, stream>>>(xb, bc, dtb, dab, D_ssm, ysb, hend, cuma);
  carry_k<<<Bn * NHn, 256, 0, stream>>>(hend, cuma);
  scancorr_k<<<Bn * NHn * 2 * TCH, 256, 0, stream>>>(bc, cuma, hend, ysb);

  gated_norm_k<<<BL, 256, 0, stream>>>(ysb, proj, norm_w, ybf);
  transpose_f2b_k<<<dim3(Hn / 32, DINn / 32), 256, 0, stream>>>(w_out, wT, DINn, Hn);
  gemm_k<1, float><<<dim3(Hn / 128, BL / 128), 256, 0, stream>>>(
      ybf, wT, resid, hidden, DINn, DINn, Hn);

  // ---- MLP ----
  rmsnorm_f32_k<<<BL, 256, 0, stream>>>(resid, ln2_w, hln);
  transpose_f2b_k<<<dim3(2 * FFn / 32, Hn / 32), 256, 0, stream>>>(w_gu, wT, Hn, 2 * FFn);
  gemm_k<0, bf16><<<dim3(2 * FFn / 128, BL / 128), 256, 0, stream>>>(
      hln, wT, gu, nullptr, Hn, Hn, 2 * FFn);
  act_k<<<BL * FFn / 8 / 256, 256, 0, stream>>>(gu);
  transpose_f2b_k<<<dim3(Hn / 32, FFn / 32), 256, 0, stream>>>(w_dn, wT, FFn, Hn);
  gemm_k<0, float><<<dim3(Hn / 128, BL / 128), 256, 0, stream>>>(
      gu, wT, h_out, nullptr, FFn, 2 * FFn, Hn);
}

// Round 8
// 1295.764 us; speedup vs baseline: 2.0263x; 2.0263x over previous
//
#include <hip/hip_runtime.h>
#include <hip/hip_bf16.h>
#include <stdint.h>

typedef __hip_bfloat16 bf16;
typedef __attribute__((ext_vector_type(8))) short bf16x8s;   // MFMA A/B fragment (8 bf16)
typedef __attribute__((ext_vector_type(4))) float f32x4;     // MFMA accumulator
typedef __attribute__((ext_vector_type(8))) unsigned short us8;

#define DEV __device__ __forceinline__
#define MFMA16(a, b, c) __builtin_amdgcn_mfma_f32_16x16x32_bf16(a, b, c, 0, 0, 0)

// ---- problem dims ----
static constexpr int Bn = 2, Ln = 2048, Hn = 2048, DINn = 4096, DSn = 128;
static constexpr int NHn = 64, FFn = 8192;
static constexpr int CONVD = DINn + 2 * DSn;            // 4352
static constexpr int DPROJ = 2 * DINn + 2 * DSn + NHn;  // 8512
static constexpr int DPROJP = 8576;                     // padded to 128 multiple (for GEMM grid)
static constexpr int BL = Bn * Ln;                      // 4096
static constexpr int LC2 = 64, NCH = Ln / LC2;          // SSD: 32 chunks x 64 steps

DEV float bf2f(unsigned short x) {
  union { unsigned int u; float f; } v; v.u = ((unsigned int)x) << 16; return v.f;
}
DEV float bfload(const bf16* p) { return bf2f(*(const unsigned short*)p); }
DEV float sigmoidf_(float x) { return 1.f / (1.f + __expf(-x)); }

// ---------------- transpose fp32 [K][N] -> bf16 [N][K] ----------------
__global__ __launch_bounds__(256) void transpose_f2b_k(
    const float* __restrict__ in, bf16* __restrict__ out, int K, int N) {
  __shared__ bf16 t[32][33];
  int nb = blockIdx.x * 32, kb = blockIdx.y * 32;
  int tx = threadIdx.x & 31, ty = threadIdx.x >> 5;
#pragma unroll
  for (int r = 0; r < 32; r += 8)
    t[ty + r][tx] = __float2bfloat16(in[(size_t)(kb + ty + r) * N + nb + tx]);
  __syncthreads();
#pragma unroll
  for (int r = 0; r < 32; r += 8)
    out[(size_t)(nb + ty + r) * K + kb + tx] = t[tx][ty + r];
}

// ---------------- rmsnorm, fp32 in -> bf16 out (row = 2048) ----------------
__global__ __launch_bounds__(256) void rmsnorm_f32_k(
    const float* __restrict__ in, const float* __restrict__ g, bf16* __restrict__ out) {
  int row = blockIdx.x, tid = threadIdx.x;
  const float* rp = in + (size_t)row * Hn + tid * 8;
  float4 a = *(const float4*)rp;
  float4 b = *(const float4*)(rp + 4);
  float v[8] = {a.x, a.y, a.z, a.w, b.x, b.y, b.z, b.w};
  float ss = 0.f;
#pragma unroll
  for (int j = 0; j < 8; ++j) ss += v[j] * v[j];
#pragma unroll
  for (int o = 1; o < 64; o <<= 1) ss += __shfl_xor(ss, o, 64);
  __shared__ float red[4];
  if ((tid & 63) == 0) red[tid >> 6] = ss;
  __syncthreads();
  float sc = rsqrtf((red[0] + red[1] + red[2] + red[3]) / Hn + 1e-5f);
  float4 g0 = *(const float4*)(g + tid * 8);
  float4 g1 = *(const float4*)(g + tid * 8 + 4);
  float gv[8] = {g0.x, g0.y, g0.z, g0.w, g1.x, g1.y, g1.z, g1.w};
  us8 ov;
#pragma unroll
  for (int j = 0; j < 8; ++j)
    ((bf16*)&ov)[j] = __float2bfloat16(v[j] * sc * gv[j]);
  *(us8*)(out + (size_t)row * Hn + tid * 8) = ov;
}

// ---------------- MFMA GEMM: C[M][N] = A[M][lda] (bf16) @ Bt[Np][K]^T (bf16) ----------------
template<int EPI, typename OutT>
__global__ __launch_bounds__(256) void gemm_k(
    const bf16* __restrict__ A, const bf16* __restrict__ Bt,
    OutT* __restrict__ C, const float* __restrict__ Res,
    int K, int lda, int N) {
  __shared__ bf16 As[128 * 64];
  __shared__ bf16 Bs[128 * 64];
  int m0 = blockIdx.y * 128, n0 = blockIdx.x * 128;
  int tid = threadIdx.x;
  int lane = tid & 63;
  int wid = tid >> 6;
  int wr = wid >> 1, wc = wid & 1;
  f32x4 acc[4][4] = {};
  int srow = tid >> 3;
  int scol = (tid & 7) * 8;
  const bf16* Ag = A + (size_t)(m0 + srow) * lda + scol;
  const bf16* Bg = Bt + (size_t)(n0 + srow) * K + scol;
  char* AsB = (char*)As;
  char* BsB = (char*)Bs;
  for (int k0 = 0; k0 < K; k0 += 64) {
#pragma unroll
    for (int i = 0; i < 4; ++i)
      __builtin_amdgcn_global_load_lds(
          (const __attribute__((address_space(1))) unsigned int*)(Ag + (size_t)i * 32 * lda + k0),
          (__attribute__((address_space(3))) unsigned int*)(AsB + i * 4096 + tid * 16),
          16, 0, 0);
#pragma unroll
    for (int i = 0; i < 4; ++i)
      __builtin_amdgcn_global_load_lds(
          (const __attribute__((address_space(1))) unsigned int*)(Bg + (size_t)i * 32 * K + k0),
          (__attribute__((address_space(3))) unsigned int*)(BsB + i * 4096 + tid * 16),
          16, 0, 0);
    __syncthreads();
#pragma unroll
    for (int kk = 0; kk < 2; ++kk) {
      int krow = kk * 32 + (lane >> 4) * 8;
      bf16x8s af[4], bfv[4];
#pragma unroll
      for (int m = 0; m < 4; ++m)
        af[m] = *(const bf16x8s*)(As + (wr * 64 + m * 16 + (lane & 15)) * 64 + krow);
#pragma unroll
      for (int n = 0; n < 4; ++n)
        bfv[n] = *(const bf16x8s*)(Bs + (wc * 64 + n * 16 + (lane & 15)) * 64 + krow);
#pragma unroll
      for (int m = 0; m < 4; ++m)
#pragma unroll
        for (int n = 0; n < 4; ++n)
          acc[m][n] = MFMA16(af[m], bfv[n], acc[m][n]);
    }
    __syncthreads();
  }
#pragma unroll
  for (int m = 0; m < 4; ++m) {
#pragma unroll
    for (int n = 0; n < 4; ++n) {
      int col = n0 + wc * 64 + n * 16 + (lane & 15);
      if (col < N) {
#pragma unroll
        for (int r = 0; r < 4; ++r) {
          int row = m0 + wr * 64 + m * 16 + (lane >> 4) * 4 + r;
          float vv = acc[m][n][r];
          if (EPI == 1) vv += Res[(size_t)row * N + col];
          if constexpr (__is_same(OutT, float)) C[(size_t)row * N + col] = vv;
          else C[(size_t)row * N + col] = __float2bfloat16(vv);
        }
      }
    }
  }
}

// ---------------- depthwise causal conv (DCONV=4) + bias + silu ----------------
// x part (c<DIN) -> xb bf16; B/C part -> bc bf16 [bt][256]
__global__ __launch_bounds__(256) void conv_silu_k(
    const bf16* __restrict__ proj, const float* __restrict__ cw,
    const float* __restrict__ cb, bf16* __restrict__ xb, bf16* __restrict__ bc) {
  int c = blockIdx.x * 256 + threadIdx.x;   // < CONVD
  int bt = blockIdx.y;
  int l = bt & (Ln - 1);
  const bf16* base = proj + (size_t)bt * DPROJ + DINn + c;
  float acc = cb[c];
#pragma unroll
  for (int k = 0; k < 4; ++k) {
    int dl = l - 3 + k;
    if (dl >= 0) acc += bfload(base + (ptrdiff_t)(k - 3) * DPROJ) * cw[c * 4 + k];
  }
  float r = acc * sigmoidf_(acc);
  if (c < DINn) xb[(size_t)bt * DINn + c] = __float2bfloat16(r);
  else          bc[(size_t)bt * 256 + (c - DINn)] = __float2bfloat16(r);
}

// ---------------- dt = softplus(raw + bias), la = dt * A  (log of dA) ----------------
__global__ __launch_bounds__(256) void dtda_k(
    const bf16* __restrict__ proj, const float* __restrict__ dt_bias,
    const float* __restrict__ A_log, float* __restrict__ dt, float* __restrict__ la) {
  int i = blockIdx.x * 256 + threadIdx.x;   // BL*NH
  int bt = i >> 6, h = i & 63;
  float raw = bfload(proj + (size_t)bt * DPROJ + (DINn + CONVD) + h) + dt_bias[h];
  float dtv = raw > 20.f ? raw : log1pf(expf(raw));
  float Ah = -expf(A_log[h]);
  dt[i] = dtv;
  la[i] = dtv * Ah;
}

// ---------------- per-chunk inclusive cumsum of la -> sarr [b][h][t] ----------------
// grid 128 = (b,h). 256 thr = 32 chunks x 8 lanes; each lane 8 serial elems + shfl scan.
__global__ __launch_bounds__(256) void cumsum_k(
    const float* __restrict__ la, float* __restrict__ sarr) {
  int blk = blockIdx.x;             // b*64 + h
  int b = blk >> 6, h = blk & 63;
  int tid = threadIdx.x;
  int ch = tid >> 3, l8 = tid & 7;
  int t0 = ch * LC2 + l8 * 8;
  const float* lp = la + ((size_t)b * Ln + t0) * NHn + h;
  float v[8];
#pragma unroll
  for (int k = 0; k < 8; ++k) v[k] = lp[(size_t)k * NHn];
#pragma unroll
  for (int k = 1; k < 8; ++k) v[k] += v[k - 1];
  float tot = v[7];
  float run = tot;
#pragma unroll
  for (int d = 1; d < 8; d <<= 1) {
    float u = __shfl_up(run, d, 8);
    if (l8 >= d) run += u;
  }
  float excl = run - tot;
  float* out = sarr + (size_t)blk * Ln + t0;
#pragma unroll
  for (int k = 0; k < 8; ++k) out[k] = excl + v[k];
}

// ---------------- SSD K1: intra-chunk Y + local chunk-end state ----------------
// grid 4096 = (b, h, ch). 256 thr = 4 waves (2x2).
// Y_intra = (mask .* (C @ B^T) .* dt_j) @ X ; Hend[p][s] = sum_j x_j[p]*dt_j*exp(sLast-s_j)*B_j[s]
__global__ __launch_bounds__(256) void ssd1_k(
    const bf16* __restrict__ xb, const bf16* __restrict__ bc,
    const float* __restrict__ dtb, const float* __restrict__ sarr,
    bf16* __restrict__ ys, bf16* __restrict__ hend) {
  __shared__ bf16 Bs[64][136];    // B[j][s]
  __shared__ bf16 Cs[64][136];    // C[i][s]
  __shared__ bf16 BdT[128][72];   // (dt_j*exp(sLast-s_j)*B[j][s])^T -> [s][j]
  __shared__ bf16 XTs[64][72];    // x^T [p][j]
  __shared__ bf16 Ss[64][72];     // masked S [i][j]
  __shared__ float sA[64];
  __shared__ float dts[64];
  int idx = blockIdx.x;
  int ch = idx & (NCH - 1), h = (idx >> 5) & 63, b = idx >> 11;
  int tid = threadIdx.x;
  size_t bt0 = (size_t)b * Ln + ch * LC2;
  if (tid < 64) {
    sA[tid] = sarr[(size_t)(b * 64 + h) * Ln + ch * LC2 + tid];
    dts[tid] = dtb[(bt0 + tid) * NHn + h];
  }
  __syncthreads();
  float sLast = sA[63];
  {
    // stage B (raw + decayed-transposed) and C. q uniform per wave.
    int j = tid & 63, q = tid >> 6;
    float wj = dts[j] * __expf(sLast - sA[j]);
    const bf16* src = bc + (bt0 + j) * 256 + q * 64;
#pragma unroll
    for (int m8 = 0; m8 < 8; ++m8) {
      us8 v = *(const us8*)(src + m8 * 8);
      if (q < 2) {
        *(us8*)&Bs[j][q * 64 + m8 * 8] = v;
#pragma unroll
        for (int e = 0; e < 8; ++e)
          BdT[q * 64 + m8 * 8 + e][j] = __float2bfloat16(bf2f(v[e]) * wj);
      } else {
        *(us8*)&Cs[j][(q - 2) * 64 + m8 * 8] = v;
      }
    }
  }
  {
    // stage X^T (pure x)
    int j = tid & 63, q = tid >> 6;
    const bf16* src = xb + (bt0 + j) * DINn + h * 64 + q * 16;
    us8 v0 = *(const us8*)src;
    us8 v1 = *(const us8*)(src + 8);
#pragma unroll
    for (int e = 0; e < 8; ++e) XTs[q * 16 + e][j] = *(const bf16*)&((unsigned short*)&v0)[e];
#pragma unroll
    for (int e = 0; e < 8; ++e) XTs[q * 16 + 8 + e][j] = *(const bf16*)&((unsigned short*)&v1)[e];
  }
  __syncthreads();
  int lane = tid & 63, wid = tid >> 6;
  int wr = wid >> 1, wc = wid & 1;
  int l15 = lane & 15, l4 = lane >> 4;
  // GEMM1: G = C @ B^T  [64x64], K=128
  f32x4 acc1[2][2] = {};
#pragma unroll
  for (int kk = 0; kk < 4; ++kk) {
    int kr = kk * 32 + l4 * 8;
    bf16x8s a0 = *(const bf16x8s*)&Cs[wr * 32 + l15][kr];
    bf16x8s a1 = *(const bf16x8s*)&Cs[wr * 32 + 16 + l15][kr];
    bf16x8s b0 = *(const bf16x8s*)&Bs[wc * 32 + l15][kr];
    bf16x8s b1 = *(const bf16x8s*)&Bs[wc * 32 + 16 + l15][kr];
    acc1[0][0] = MFMA16(a0, b0, acc1[0][0]);
    acc1[0][1] = MFMA16(a0, b1, acc1[0][1]);
    acc1[1][0] = MFMA16(a1, b0, acc1[1][0]);
    acc1[1][1] = MFMA16(a1, b1, acc1[1][1]);
  }
  // mask: S[i][j] = (i>=j) ? exp(s_i - s_j)*G*dt_j : 0
#pragma unroll
  for (int m = 0; m < 2; ++m)
#pragma unroll
    for (int n = 0; n < 2; ++n) {
      int j = wc * 32 + n * 16 + l15;
      float sj = sA[j], dj = dts[j];
#pragma unroll
      for (int r = 0; r < 4; ++r) {
        int i = wr * 32 + m * 16 + l4 * 4 + r;
        float val = (i >= j) ? __expf(sA[i] - sj) * acc1[m][n][r] * dj : 0.f;
        Ss[i][j] = __float2bfloat16(val);
      }
    }
  __syncthreads();
  // GEMM2: Y_intra = S @ X  -> D[i][p], K=64
  f32x4 acc2[2][2] = {};
#pragma unroll
  for (int kk = 0; kk < 2; ++kk) {
    int kr = kk * 32 + l4 * 8;
    bf16x8s a0 = *(const bf16x8s*)&Ss[wr * 32 + l15][kr];
    bf16x8s a1 = *(const bf16x8s*)&Ss[wr * 32 + 16 + l15][kr];
    bf16x8s b0 = *(const bf16x8s*)&XTs[wc * 32 + l15][kr];
    bf16x8s b1 = *(const bf16x8s*)&XTs[wc * 32 + 16 + l15][kr];
    acc2[0][0] = MFMA16(a0, b0, acc2[0][0]);
    acc2[0][1] = MFMA16(a0, b1, acc2[0][1]);
    acc2[1][0] = MFMA16(a1, b0, acc2[1][0]);
    acc2[1][1] = MFMA16(a1, b1, acc2[1][1]);
  }
#pragma unroll
  for (int m = 0; m < 2; ++m)
#pragma unroll
    for (int n = 0; n < 2; ++n) {
      int p = wc * 32 + n * 16 + l15;
#pragma unroll
      for (int r = 0; r < 4; ++r) {
        int i = wr * 32 + m * 16 + l4 * 4 + r;
        ys[(bt0 + i) * DINn + h * 64 + p] = __float2bfloat16(acc2[m][n][r]);
      }
    }
  // GEMM3: Hend[p][s] = X^T @ BdT^T, M=p(64), N=s(128), K=64
  f32x4 acc3[2][4] = {};
#pragma unroll
  for (int kk = 0; kk < 2; ++kk) {
    int kr = kk * 32 + l4 * 8;
    bf16x8s a0 = *(const bf16x8s*)&XTs[wr * 32 + l15][kr];
    bf16x8s a1 = *(const bf16x8s*)&XTs[wr * 32 + 16 + l15][kr];
#pragma unroll
    for (int n = 0; n < 4; ++n) {
      bf16x8s bb = *(const bf16x8s*)&BdT[wc * 64 + n * 16 + l15][kr];
      acc3[0][n] = MFMA16(a0, bb, acc3[0][n]);
      acc3[1][n] = MFMA16(a1, bb, acc3[1][n]);
    }
  }
  bf16* hb = hend + ((size_t)((b * 64 + h) * NCH + ch)) * 8192;
#pragma unroll
  for (int m = 0; m < 2; ++m)
#pragma unroll
    for (int n = 0; n < 4; ++n) {
      int s = wc * 64 + n * 16 + l15;
#pragma unroll
      for (int r = 0; r < 4; ++r) {
        int p = wr * 32 + m * 16 + l4 * 4 + r;
        hb[p * 128 + s] = __float2bfloat16(acc3[m][n][r]);
      }
    }
}

// ---------------- SSD K2: carry propagation, in-place hend -> hinit (bf16, fp32 accum) ----------------
__global__ __launch_bounds__(256) void carry_k(
    bf16* __restrict__ hend, const float* __restrict__ sarr) {
  int blk = blockIdx.x;  // b*64 + h
  int tid = threadIdx.x;
  bf16* base = hend + (size_t)blk * NCH * 8192 + tid * 32;
  const float* sp = sarr + (size_t)blk * Ln;
  float c[32];
#pragma unroll
  for (int i = 0; i < 32; ++i) c[i] = 0.f;
  for (int j = 0; j < NCH; ++j) {
    float aT = __expf(sp[j * LC2 + LC2 - 1]);
    bf16* pj = base + (size_t)j * 8192;
    float tmp[32];
#pragma unroll
    for (int q = 0; q < 4; ++q) {
      us8 v = ((const us8*)pj)[q];
#pragma unroll
      for (int e = 0; e < 8; ++e) tmp[q * 8 + e] = bf2f(v[e]);
    }
#pragma unroll
    for (int q = 0; q < 4; ++q) {
      us8 o;
#pragma unroll
      for (int e = 0; e < 8; ++e) ((bf16*)&o)[e] = __float2bfloat16(c[q * 8 + e]);
      ((us8*)pj)[q] = o;
    }
#pragma unroll
    for (int i = 0; i < 32; ++i) c[i] = fmaf(aT, c[i], tmp[i]);
  }
}

// ---------------- SSD K3: Y += (exp(s_i)*C_i) @ Hinit^T ----------------
__global__ __launch_bounds__(256) void ssd2_k(
    const bf16* __restrict__ bc, const float* __restrict__ sarr,
    const bf16* __restrict__ hinit, bf16* __restrict__ ys) {
  __shared__ bf16 Ce[64][136];
  __shared__ bf16 Hs[64][136];
  __shared__ float sA[64];
  int idx = blockIdx.x;
  int ch = idx & (NCH - 1), h = (idx >> 5) & 63, b = idx >> 11;
  int tid = threadIdx.x;
  size_t bt0 = (size_t)b * Ln + ch * LC2;
  if (tid < 64) sA[tid] = sarr[(size_t)(b * 64 + h) * Ln + ch * LC2 + tid];
  __syncthreads();
  {
    int i = tid & 63, q = tid >> 6;
    float ei = __expf(sA[i]);
    const bf16* src = bc + (bt0 + i) * 256 + 128 + q * 32;
#pragma unroll
    for (int m8 = 0; m8 < 4; ++m8) {
      us8 v = *(const us8*)(src + m8 * 8);
      us8 o;
#pragma unroll
      for (int e = 0; e < 8; ++e) ((bf16*)&o)[e] = __float2bfloat16(bf2f(v[e]) * ei);
      *(us8*)&Ce[i][q * 32 + m8 * 8] = o;
    }
    const bf16* hsrc = hinit + ((size_t)((b * 64 + h) * NCH + ch)) * 8192 + i * 128 + q * 32;
#pragma unroll
    for (int m8 = 0; m8 < 4; ++m8)
      *(us8*)&Hs[i][q * 32 + m8 * 8] = *(const us8*)(hsrc + m8 * 8);
  }
  __syncthreads();
  int lane = tid & 63, wid = tid >> 6;
  int wr = wid >> 1, wc = wid & 1;
  int l15 = lane & 15, l4 = lane >> 4;
  f32x4 acc[2][2] = {};
#pragma unroll
  for (int kk = 0; kk < 4; ++kk) {
    int kr = kk * 32 + l4 * 8;
    bf16x8s a0 = *(const bf16x8s*)&Ce[wr * 32 + l15][kr];
    bf16x8s a1 = *(const bf16x8s*)&Ce[wr * 32 + 16 + l15][kr];
    bf16x8s b0 = *(const bf16x8s*)&Hs[wc * 32 + l15][kr];
    bf16x8s b1 = *(const bf16x8s*)&Hs[wc * 32 + 16 + l15][kr];
    acc[0][0] = MFMA16(a0, b0, acc[0][0]);
    acc[0][1] = MFMA16(a0, b1, acc[0][1]);
    acc[1][0] = MFMA16(a1, b0, acc[1][0]);
    acc[1][1] = MFMA16(a1, b1, acc[1][1]);
  }
#pragma unroll
  for (int m = 0; m < 2; ++m)
#pragma unroll
    for (int n = 0; n < 2; ++n) {
      int p = wc * 32 + n * 16 + l15;
#pragma unroll
      for (int r = 0; r < 4; ++r) {
        int i = wr * 32 + m * 16 + l4 * 4 + r;
        bf16* yy = &ys[(bt0 + i) * DINn + h * 64 + p];
        *yy = __float2bfloat16(bfload(yy) + acc[m][n][r]);
      }
    }
}

// ---------------- gated rmsnorm (+ D*x): out = rmsnorm((y + D*x) * silu(z)) * w ----------------
__global__ __launch_bounds__(256) void gated_norm_k(
    const bf16* __restrict__ ys, const bf16* __restrict__ xb,
    const float* __restrict__ Dp, const bf16* __restrict__ proj,
    const float* __restrict__ gw, bf16* __restrict__ out) {
  int row = blockIdx.x, tid = threadIdx.x;
  const bf16* yr = ys + (size_t)row * DINn;
  const bf16* xr = xb + (size_t)row * DINn;
  const bf16* zr = proj + (size_t)row * DPROJ;
  float v[2][8];
  float ss = 0.f;
#pragma unroll
  for (int it = 0; it < 2; ++it) {
    int base = (it * 256 + tid) * 8;
    float Dh = Dp[base >> 6];
    us8 y = *(const us8*)(yr + base);
    us8 x = *(const us8*)(xr + base);
    us8 z = *(const us8*)(zr + base);
#pragma unroll
    for (int j = 0; j < 8; ++j) {
      float zf = bf2f(z[j]);
      float val = (bf2f(y[j]) + Dh * bf2f(x[j])) * zf * sigmoidf_(zf);
      v[it][j] = val; ss += val * val;
    }
  }
#pragma unroll
  for (int o = 1; o < 64; o <<= 1) ss += __shfl_xor(ss, o, 64);
  __shared__ float red[4];
  if ((tid & 63) == 0) red[tid >> 6] = ss;
  __syncthreads();
  float sc = rsqrtf((red[0] + red[1] + red[2] + red[3]) / DINn + 1e-5f);
#pragma unroll
  for (int it = 0; it < 2; ++it) {
    int base = (it * 256 + tid) * 8;
    float4 g0 = *(const float4*)(gw + base);
    float4 g1 = *(const float4*)(gw + base + 4);
    float gv[8] = {g0.x, g0.y, g0.z, g0.w, g1.x, g1.y, g1.z, g1.w};
    us8 ov;
#pragma unroll
    for (int j = 0; j < 8; ++j)
      ((bf16*)&ov)[j] = __float2bfloat16(v[it][j] * sc * gv[j]);
    *(us8*)(out + (size_t)row * DINn + base) = ov;
  }
}

// ---------------- swiglu act, IN-PLACE on gu ----------------
__global__ __launch_bounds__(256) void act_k(bf16* __restrict__ gu) {
  int i = blockIdx.x * 256 + threadIdx.x;
  int row = i >> 10, g = i & 1023;
  bf16* rp = gu + (size_t)row * (2 * FFn) + g * 8;
  us8 a = *(const us8*)(rp);
  us8 bx = *(const us8*)(rp + FFn);
  us8 ov;
#pragma unroll
  for (int j = 0; j < 8; ++j) {
    float av = bf2f(a[j]), bv = bf2f(bx[j]);
    ((bf16*)&ov)[j] = __float2bfloat16(av * sigmoidf_(av) * bv);
  }
  *(us8*)rp = ov;
}

// ---------------- launch ----------------
extern "C" void kernel_launch(void* const* d_in, const int* in_sizes, int n_in,
                              void* d_out, int out_size, void* d_ws, size_t ws_size,
                              hipStream_t stream) {
  (void)in_sizes; (void)n_in; (void)out_size; (void)ws_size;
  const float* hidden  = (const float*)d_in[0];
  const float* w_in    = (const float*)d_in[1];
  const float* conv_w  = (const float*)d_in[2];
  const float* conv_b  = (const float*)d_in[3];
  const float* A_log   = (const float*)d_in[4];
  const float* D_ssm   = (const float*)d_in[5];
  const float* dt_bias = (const float*)d_in[6];
  const float* norm_w  = (const float*)d_in[7];
  const float* w_out   = (const float*)d_in[8];
  const float* ln1_w   = (const float*)d_in[9];
  const float* ln2_w   = (const float*)d_in[10];
  const float* w_gu    = (const float*)d_in[11];
  const float* w_dn    = (const float*)d_in[12];

  // ---- workspace layout, 247.5 MiB peak, liveness-checked ----
  char* ws = (char*)d_ws;
  const size_t OFF_WT   = 0;                          // 67,108,864  weight-T buffer (max: w_guT)
  const size_t OFF_PROJ = 67108864ull;                // 69,730,304  proj bf16 [4096][8512]
  const size_t OFF_XB   = OFF_PROJ + 69730304ull;     // 33,554,432  conv x bf16 [4096][4096]
  const size_t OFF_BC   = OFF_XB  + 33554432ull;      //  2,097,152  conv B/C bf16 [4096][256]
  const size_t OFF_DTB  = OFF_BC  + 2097152ull;       //  1,048,576  dt fp32 [bt][64]
  const size_t OFF_LA   = OFF_DTB + 1048576ull;       //  1,048,576  log-dA fp32 [bt][64]
  const size_t OFF_SARR = OFF_LA  + 1048576ull;       //  1,048,576  chunk-cumsum fp32 [b][h][t]
  const size_t OFF_YS   = OFF_SARR + 1048576ull;      // 33,554,432  scan y bf16 [4096][4096]
  const size_t OFF_YBF  = OFF_YS  + 33554432ull;      // 33,554,432  gated-norm out bf16
  const size_t OFF_HLN  = OFF_YBF + 33554432ull;      // 16,777,216  ln out bf16 [4096][2048]
  // aliases (regions dead at write time):
  const size_t OFF_HEND = OFF_WT;                     // 67,108,864 EXACT: 128*32*8192*2; wT dead in mixer window
  const size_t OFF_GU   = OFF_PROJ;                   // 134,217,728 over proj..ys-head (dead after gated_norm)

  bf16*  wT   = (bf16*)(ws + OFF_WT);
  bf16*  proj = (bf16*)(ws + OFF_PROJ);
  bf16*  xb   = (bf16*)(ws + OFF_XB);
  bf16*  bcb  = (bf16*)(ws + OFF_BC);
  float* dtb  = (float*)(ws + OFF_DTB);
  float* la   = (float*)(ws + OFF_LA);
  float* sarr = (float*)(ws + OFF_SARR);
  bf16*  ysb  = (bf16*)(ws + OFF_YS);
  bf16*  ybf  = (bf16*)(ws + OFF_YBF);
  bf16*  hln  = (bf16*)(ws + OFF_HLN);
  bf16*  hend = (bf16*)(ws + OFF_HEND);
  bf16*  gu   = (bf16*)(ws + OFF_GU);

  float* h_out = (float*)d_out;                 // output 0: h  (fp32)
  float* resid = h_out + (size_t)BL * Hn;       // output 1: residual (fp32)

  // ---- mixer ----
  transpose_f2b_k<<<dim3(DPROJ / 32, Hn / 32), 256, 0, stream>>>(w_in, wT, Hn, DPROJ);
  hipMemsetAsync(wT + (size_t)DPROJ * Hn, 0, (size_t)(DPROJP - DPROJ) * Hn * 2, stream);
  rmsnorm_f32_k<<<BL, 256, 0, stream>>>(hidden, ln1_w, hln);
  gemm_k<0, bf16><<<dim3(DPROJP / 128, BL / 128), 256, 0, stream>>>(
      hln, wT, proj, nullptr, Hn, Hn, DPROJ);

  conv_silu_k<<<dim3(CONVD / 256, BL), 256, 0, stream>>>(proj, conv_w, conv_b, xb, bcb);
  dtda_k<<<BL * NHn / 256, 256, 0, stream>>>(proj, dt_bias, A_log, dtb, la);
  cumsum_k<<<Bn * NHn, 256, 0, stream>>>(la, sarr);

  // SSD scan (hend aliases wT)
  ssd1_k<<<Bn * NHn * NCH, 256, 0, stream>>>(xb, bcb, dtb, sarr, ysb, hend);
  carry_k<<<Bn * NHn, 256, 0, stream>>>(hend, sarr);
  ssd2_k<<<Bn * NHn * NCH, 256, 0, stream>>>(bcb, sarr, hend, ysb);

  gated_norm_k<<<BL, 256, 0, stream>>>(ysb, xb, D_ssm, proj, norm_w, ybf);
  transpose_f2b_k<<<dim3(Hn / 32, DINn / 32), 256, 0, stream>>>(w_out, wT, DINn, Hn);
  gemm_k<1, float><<<dim3(Hn / 128, BL / 128), 256, 0, stream>>>(
      ybf, wT, resid, hidden, DINn, DINn, Hn);

  // ---- MLP ----
  rmsnorm_f32_k<<<BL, 256, 0, stream>>>(resid, ln2_w, hln);
  transpose_f2b_k<<<dim3(2 * FFn / 32, Hn / 32), 256, 0, stream>>>(w_gu, wT, Hn, 2 * FFn);
  gemm_k<0, bf16><<<dim3(2 * FFn / 128, BL / 128), 256, 0, stream>>>(
      hln, wT, gu, nullptr, Hn, Hn, 2 * FFn);
  act_k<<<BL * FFn / 8 / 256, 256, 0, stream>>>(gu);
  transpose_f2b_k<<<dim3(Hn / 32, FFn / 32), 256, 0, stream>>>(w_dn, wT, FFn, Hn);
  gemm_k<0, float><<<dim3(Hn / 128, BL / 128), 256, 0, stream>>>(
      gu, wT, h_out, nullptr, FFn, 2 * FFn, Hn);
}

// Round 9
// 1033.625 us; speedup vs baseline: 2.5402x; 1.2536x over previous
//
#include <hip/hip_runtime.h>
#include <hip/hip_bf16.h>
#include <stdint.h>

typedef __hip_bfloat16 bf16;
typedef __attribute__((ext_vector_type(8))) short bf16x8s;   // MFMA A/B fragment (8 bf16)
typedef __attribute__((ext_vector_type(4))) float f32x4;     // MFMA accumulator
typedef __attribute__((ext_vector_type(8))) unsigned short us8;

#define DEV __device__ __forceinline__
#define MFMA16(a, b, c) __builtin_amdgcn_mfma_f32_16x16x32_bf16(a, b, c, 0, 0, 0)
#define AS1 __attribute__((address_space(1)))
#define AS3 __attribute__((address_space(3)))

// ---- problem dims ----
static constexpr int Bn = 2, Ln = 2048, Hn = 2048, DINn = 4096, DSn = 128;
static constexpr int NHn = 64, FFn = 8192;
static constexpr int CONVD = DINn + 2 * DSn;            // 4352
static constexpr int DPROJ = 2 * DINn + 2 * DSn + NHn;  // 8512
static constexpr int DPROJP = 8704;                     // padded to 256 multiple (GEMM grid)
static constexpr int BL = Bn * Ln;                      // 4096
static constexpr int LC2 = 64, NCH = Ln / LC2;          // SSD: 32 chunks x 64 steps

DEV float bf2f(unsigned short x) {
  union { unsigned int u; float f; } v; v.u = ((unsigned int)x) << 16; return v.f;
}
DEV float bfload(const bf16* p) { return bf2f(*(const unsigned short*)p); }
DEV float sigmoidf_(float x) { return 1.f / (1.f + __expf(-x)); }

// ---------------- transpose fp32 [K][N] -> bf16 [N][K] ----------------
__global__ __launch_bounds__(256) void transpose_f2b_k(
    const float* __restrict__ in, bf16* __restrict__ out, int K, int N) {
  __shared__ bf16 t[32][33];
  int nb = blockIdx.x * 32, kb = blockIdx.y * 32;
  int tx = threadIdx.x & 31, ty = threadIdx.x >> 5;
#pragma unroll
  for (int r = 0; r < 32; r += 8)
    t[ty + r][tx] = __float2bfloat16(in[(size_t)(kb + ty + r) * N + nb + tx]);
  __syncthreads();
#pragma unroll
  for (int r = 0; r < 32; r += 8)
    out[(size_t)(nb + ty + r) * K + kb + tx] = t[tx][ty + r];
}

// ---------------- rmsnorm, fp32 in -> bf16 out (row = 2048) ----------------
__global__ __launch_bounds__(256) void rmsnorm_f32_k(
    const float* __restrict__ in, const float* __restrict__ g, bf16* __restrict__ out) {
  int row = blockIdx.x, tid = threadIdx.x;
  const float* rp = in + (size_t)row * Hn + tid * 8;
  float4 a = *(const float4*)rp;
  float4 b = *(const float4*)(rp + 4);
  float v[8] = {a.x, a.y, a.z, a.w, b.x, b.y, b.z, b.w};
  float ss = 0.f;
#pragma unroll
  for (int j = 0; j < 8; ++j) ss += v[j] * v[j];
#pragma unroll
  for (int o = 1; o < 64; o <<= 1) ss += __shfl_xor(ss, o, 64);
  __shared__ float red[4];
  if ((tid & 63) == 0) red[tid >> 6] = ss;
  __syncthreads();
  float sc = rsqrtf((red[0] + red[1] + red[2] + red[3]) / Hn + 1e-5f);
  float4 g0 = *(const float4*)(g + tid * 8);
  float4 g1 = *(const float4*)(g + tid * 8 + 4);
  float gv[8] = {g0.x, g0.y, g0.z, g0.w, g1.x, g1.y, g1.z, g1.w};
  us8 ov;
#pragma unroll
  for (int j = 0; j < 8; ++j)
    ((bf16*)&ov)[j] = __float2bfloat16(v[j] * sc * gv[j]);
  *(us8*)(out + (size_t)row * Hn + tid * 8) = ov;
}

// ---------------- pipelined MFMA GEMM ----------------
// BM = MF*32 (MF=8 -> 256, MF=4 -> 128), BN = 256, BK = 32. 512 threads = 8 waves (2x4).
// 3 LDS buffers; stage tile t+2 while computing t; counted vmcnt (never 0 in-loop);
// raw s_barrier (no full drain); T2 swizzle byte^=((row>>1)&3)<<4 via pre-swizzled
// global source (linear LDS dest) + swizzled ds_read; T5 setprio around MFMA cluster.
// Bt is [Npad][K], row-major K-contiguous; grid nwg % 8 == 0 (bijective XCD swizzle).
template<int MF, int EPI, typename OutT>
__global__ __launch_bounds__(512, (MF == 8 ? 2 : 4)) void gemm256_k(
    const bf16* __restrict__ A, const bf16* __restrict__ Bt,
    OutT* __restrict__ C, const float* __restrict__ Res,
    int K, int lda, int N, int nbx) {
  constexpr int BM = MF * 32;
  __shared__ bf16 Abuf[3][BM * 32];
  __shared__ bf16 Bbuf[3][256 * 32];
  int nwg = gridDim.x;
  int orig = blockIdx.x;
  int wg = (orig & 7) * (nwg >> 3) + (orig >> 3);   // XCD-contiguous chunks
  int bx = wg % nbx, by = wg / nbx;
  int m0 = by * BM, n0 = bx * 256;
  int tid = threadIdx.x;
  int lane = tid & 63, wid = tid >> 6;
  int wr = wid >> 2, wc = wid & 3;
  int l15 = lane & 15, l4 = lane >> 4;

  // staging: physical P = tid*16 (+8192); logical L = P ^ (((P>>7)&3)<<4)
  int P0 = tid * 16;
  int P1 = 8192 + tid * 16;
  int L0 = P0 ^ (((P0 >> 7) & 3) << 4);
  int L1 = P1 ^ (((P1 >> 7) & 3) << 4);
  int ar1 = (MF == 8) ? (L1 >> 6) : 0;
  const bf16* Ag0 = A + (size_t)(m0 + (L0 >> 6)) * lda + ((L0 >> 4) & 3) * 8;
  const bf16* Ag1 = A + (size_t)(m0 + ar1) * lda + ((L1 >> 4) & 3) * 8;
  const bf16* Bg0 = Bt + (size_t)(n0 + (L0 >> 6)) * K + ((L0 >> 4) & 3) * 8;
  const bf16* Bg1 = Bt + (size_t)(n0 + (L1 >> 6)) * K + ((L1 >> 4) & 3) * 8;

  auto stage = [&](int bi, int k0) {
    char* ab = (char*)&Abuf[bi][0];
    char* bb = (char*)&Bbuf[bi][0];
    __builtin_amdgcn_global_load_lds((const AS1 unsigned int*)(Ag0 + k0), (AS3 unsigned int*)(ab + P0), 16, 0, 0);
    if constexpr (MF == 8)
      __builtin_amdgcn_global_load_lds((const AS1 unsigned int*)(Ag1 + k0), (AS3 unsigned int*)(ab + P1), 16, 0, 0);
    __builtin_amdgcn_global_load_lds((const AS1 unsigned int*)(Bg0 + k0), (AS3 unsigned int*)(bb + P0), 16, 0, 0);
    __builtin_amdgcn_global_load_lds((const AS1 unsigned int*)(Bg1 + k0), (AS3 unsigned int*)(bb + P1), 16, 0, 0);
  };

  f32x4 acc[MF][4] = {};
  int arow0 = wr * (MF * 16) + l15;
  int acol = (l4 * 16) ^ (((arow0 >> 1) & 3) << 4);   // swizzled byte col (m*16 doesn't affect swz bits)
  int brow0 = wc * 64 + l15;
  int bcol = (l4 * 16) ^ (((brow0 >> 1) & 3) << 4);
  int NT = K >> 5;

  stage(0, 0);
  stage(1, 32);
  if constexpr (MF == 8) asm volatile("s_waitcnt vmcnt(4)" ::: "memory");
  else                   asm volatile("s_waitcnt vmcnt(3)" ::: "memory");
  __builtin_amdgcn_s_barrier();
  asm volatile("" ::: "memory");

  for (int t = 0; t < NT; ++t) {
    const char* Ab = (const char*)&Abuf[t % 3][0];
    const char* Bb = (const char*)&Bbuf[t % 3][0];
    bf16x8s af[MF], bfv[4];
#pragma unroll
    for (int m = 0; m < MF; ++m)
      af[m] = *(const bf16x8s*)(Ab + (arow0 + m * 16) * 64 + acol);
#pragma unroll
    for (int n = 0; n < 4; ++n)
      bfv[n] = *(const bf16x8s*)(Bb + (brow0 + n * 16) * 64 + bcol);
    if (t + 2 < NT) stage((t + 2) % 3, (t + 2) * 32);
    __builtin_amdgcn_s_setprio(1);
#pragma unroll
    for (int m = 0; m < MF; ++m)
#pragma unroll
      for (int n = 0; n < 4; ++n)
        acc[m][n] = MFMA16(af[m], bfv[n], acc[m][n]);
    __builtin_amdgcn_s_setprio(0);
    if (t + 2 < NT) {
      if constexpr (MF == 8) asm volatile("s_waitcnt vmcnt(4)" ::: "memory");
      else                   asm volatile("s_waitcnt vmcnt(3)" ::: "memory");
    } else {
      asm volatile("s_waitcnt vmcnt(0)" ::: "memory");
    }
    __builtin_amdgcn_s_barrier();
    asm volatile("" ::: "memory");
  }

#pragma unroll
  for (int m = 0; m < MF; ++m) {
    int row = m0 + wr * (MF * 16) + m * 16 + l4 * 4;
#pragma unroll
    for (int n = 0; n < 4; ++n) {
      int col = n0 + wc * 64 + n * 16 + l15;
      if (col < N) {
#pragma unroll
        for (int r = 0; r < 4; ++r) {
          float vv = acc[m][n][r];
          if (EPI == 1) vv += Res[(size_t)(row + r) * N + col];
          if constexpr (__is_same(OutT, float)) C[(size_t)(row + r) * N + col] = vv;
          else C[(size_t)(row + r) * N + col] = __float2bfloat16(vv);
        }
      }
    }
  }
}

// ---------------- depthwise causal conv (DCONV=4) + bias + silu ----------------
__global__ __launch_bounds__(256) void conv_silu_k(
    const bf16* __restrict__ proj, const float* __restrict__ cw,
    const float* __restrict__ cb, bf16* __restrict__ xb, bf16* __restrict__ bc) {
  int c = blockIdx.x * 256 + threadIdx.x;   // < CONVD
  int bt = blockIdx.y;
  int l = bt & (Ln - 1);
  const bf16* base = proj + (size_t)bt * DPROJ + DINn + c;
  float acc = cb[c];
#pragma unroll
  for (int k = 0; k < 4; ++k) {
    int dl = l - 3 + k;
    if (dl >= 0) acc += bfload(base + (ptrdiff_t)(k - 3) * DPROJ) * cw[c * 4 + k];
  }
  float r = acc * sigmoidf_(acc);
  if (c < DINn) xb[(size_t)bt * DINn + c] = __float2bfloat16(r);
  else          bc[(size_t)bt * 256 + (c - DINn)] = __float2bfloat16(r);
}

// ---------------- dt = softplus(raw + bias), la = dt * A  (log of dA) ----------------
__global__ __launch_bounds__(256) void dtda_k(
    const bf16* __restrict__ proj, const float* __restrict__ dt_bias,
    const float* __restrict__ A_log, float* __restrict__ dt, float* __restrict__ la) {
  int i = blockIdx.x * 256 + threadIdx.x;   // BL*NH
  int bt = i >> 6, h = i & 63;
  float raw = bfload(proj + (size_t)bt * DPROJ + (DINn + CONVD) + h) + dt_bias[h];
  float dtv = raw > 20.f ? raw : log1pf(expf(raw));
  float Ah = -expf(A_log[h]);
  dt[i] = dtv;
  la[i] = dtv * Ah;
}

// ---------------- per-chunk inclusive cumsum of la -> sarr [b][h][t] ----------------
__global__ __launch_bounds__(256) void cumsum_k(
    const float* __restrict__ la, float* __restrict__ sarr) {
  int blk = blockIdx.x;             // b*64 + h
  int b = blk >> 6, h = blk & 63;
  int tid = threadIdx.x;
  int ch = tid >> 3, l8 = tid & 7;
  int t0 = ch * LC2 + l8 * 8;
  const float* lp = la + ((size_t)b * Ln + t0) * NHn + h;
  float v[8];
#pragma unroll
  for (int k = 0; k < 8; ++k) v[k] = lp[(size_t)k * NHn];
#pragma unroll
  for (int k = 1; k < 8; ++k) v[k] += v[k - 1];
  float tot = v[7];
  float run = tot;
#pragma unroll
  for (int d = 1; d < 8; d <<= 1) {
    float u = __shfl_up(run, d, 8);
    if (l8 >= d) run += u;
  }
  float excl = run - tot;
  float* out = sarr + (size_t)blk * Ln + t0;
#pragma unroll
  for (int k = 0; k < 8; ++k) out[k] = excl + v[k];
}

// ---------------- SSD K1: intra-chunk Y + local chunk-end state ----------------
__global__ __launch_bounds__(256) void ssd1_k(
    const bf16* __restrict__ xb, const bf16* __restrict__ bc,
    const float* __restrict__ dtb, const float* __restrict__ sarr,
    bf16* __restrict__ ys, bf16* __restrict__ hend) {
  __shared__ bf16 Bs[64][136];    // B[j][s]
  __shared__ bf16 Cs[64][136];    // C[i][s]
  __shared__ bf16 BdT[128][72];   // (dt_j*exp(sLast-s_j)*B[j][s])^T -> [s][j]
  __shared__ bf16 XTs[64][72];    // x^T [p][j]
  __shared__ bf16 Ss[64][72];     // masked S [i][j]
  __shared__ float sA[64];
  __shared__ float dts[64];
  int idx = blockIdx.x;
  int ch = idx & (NCH - 1), h = (idx >> 5) & 63, b = idx >> 11;
  int tid = threadIdx.x;
  size_t bt0 = (size_t)b * Ln + ch * LC2;
  if (tid < 64) {
    sA[tid] = sarr[(size_t)(b * 64 + h) * Ln + ch * LC2 + tid];
    dts[tid] = dtb[(bt0 + tid) * NHn + h];
  }
  __syncthreads();
  float sLast = sA[63];
  {
    int j = tid & 63, q = tid >> 6;
    float wj = dts[j] * __expf(sLast - sA[j]);
    const bf16* src = bc + (bt0 + j) * 256 + q * 64;
#pragma unroll
    for (int m8 = 0; m8 < 8; ++m8) {
      us8 v = *(const us8*)(src + m8 * 8);
      if (q < 2) {
        *(us8*)&Bs[j][q * 64 + m8 * 8] = v;
#pragma unroll
        for (int e = 0; e < 8; ++e)
          BdT[q * 64 + m8 * 8 + e][j] = __float2bfloat16(bf2f(v[e]) * wj);
      } else {
        *(us8*)&Cs[j][(q - 2) * 64 + m8 * 8] = v;
      }
    }
  }
  {
    int j = tid & 63, q = tid >> 6;
    const bf16* src = xb + (bt0 + j) * DINn + h * 64 + q * 16;
    us8 v0 = *(const us8*)src;
    us8 v1 = *(const us8*)(src + 8);
#pragma unroll
    for (int e = 0; e < 8; ++e) XTs[q * 16 + e][j] = *(const bf16*)&((unsigned short*)&v0)[e];
#pragma unroll
    for (int e = 0; e < 8; ++e) XTs[q * 16 + 8 + e][j] = *(const bf16*)&((unsigned short*)&v1)[e];
  }
  __syncthreads();
  int lane = tid & 63, wid = tid >> 6;
  int wr = wid >> 1, wc = wid & 1;
  int l15 = lane & 15, l4 = lane >> 4;
  f32x4 acc1[2][2] = {};
#pragma unroll
  for (int kk = 0; kk < 4; ++kk) {
    int kr = kk * 32 + l4 * 8;
    bf16x8s a0 = *(const bf16x8s*)&Cs[wr * 32 + l15][kr];
    bf16x8s a1 = *(const bf16x8s*)&Cs[wr * 32 + 16 + l15][kr];
    bf16x8s b0 = *(const bf16x8s*)&Bs[wc * 32 + l15][kr];
    bf16x8s b1 = *(const bf16x8s*)&Bs[wc * 32 + 16 + l15][kr];
    acc1[0][0] = MFMA16(a0, b0, acc1[0][0]);
    acc1[0][1] = MFMA16(a0, b1, acc1[0][1]);
    acc1[1][0] = MFMA16(a1, b0, acc1[1][0]);
    acc1[1][1] = MFMA16(a1, b1, acc1[1][1]);
  }
#pragma unroll
  for (int m = 0; m < 2; ++m)
#pragma unroll
    for (int n = 0; n < 2; ++n) {
      int j = wc * 32 + n * 16 + l15;
      float sj = sA[j], dj = dts[j];
#pragma unroll
      for (int r = 0; r < 4; ++r) {
        int i = wr * 32 + m * 16 + l4 * 4 + r;
        float val = (i >= j) ? __expf(sA[i] - sj) * acc1[m][n][r] * dj : 0.f;
        Ss[i][j] = __float2bfloat16(val);
      }
    }
  __syncthreads();
  f32x4 acc2[2][2] = {};
#pragma unroll
  for (int kk = 0; kk < 2; ++kk) {
    int kr = kk * 32 + l4 * 8;
    bf16x8s a0 = *(const bf16x8s*)&Ss[wr * 32 + l15][kr];
    bf16x8s a1 = *(const bf16x8s*)&Ss[wr * 32 + 16 + l15][kr];
    bf16x8s b0 = *(const bf16x8s*)&XTs[wc * 32 + l15][kr];
    bf16x8s b1 = *(const bf16x8s*)&XTs[wc * 32 + 16 + l15][kr];
    acc2[0][0] = MFMA16(a0, b0, acc2[0][0]);
    acc2[0][1] = MFMA16(a0, b1, acc2[0][1]);
    acc2[1][0] = MFMA16(a1, b0, acc2[1][0]);
    acc2[1][1] = MFMA16(a1, b1, acc2[1][1]);
  }
#pragma unroll
  for (int m = 0; m < 2; ++m)
#pragma unroll
    for (int n = 0; n < 2; ++n) {
      int p = wc * 32 + n * 16 + l15;
#pragma unroll
      for (int r = 0; r < 4; ++r) {
        int i = wr * 32 + m * 16 + l4 * 4 + r;
        ys[(bt0 + i) * DINn + h * 64 + p] = __float2bfloat16(acc2[m][n][r]);
      }
    }
  f32x4 acc3[2][4] = {};
#pragma unroll
  for (int kk = 0; kk < 2; ++kk) {
    int kr = kk * 32 + l4 * 8;
    bf16x8s a0 = *(const bf16x8s*)&XTs[wr * 32 + l15][kr];
    bf16x8s a1 = *(const bf16x8s*)&XTs[wr * 32 + 16 + l15][kr];
#pragma unroll
    for (int n = 0; n < 4; ++n) {
      bf16x8s bb = *(const bf16x8s*)&BdT[wc * 64 + n * 16 + l15][kr];
      acc3[0][n] = MFMA16(a0, bb, acc3[0][n]);
      acc3[1][n] = MFMA16(a1, bb, acc3[1][n]);
    }
  }
  bf16* hb = hend + ((size_t)((b * 64 + h) * NCH + ch)) * 8192;
#pragma unroll
  for (int m = 0; m < 2; ++m)
#pragma unroll
    for (int n = 0; n < 4; ++n) {
      int s = wc * 64 + n * 16 + l15;
#pragma unroll
      for (int r = 0; r < 4; ++r) {
        int p = wr * 32 + m * 16 + l4 * 4 + r;
        hb[p * 128 + s] = __float2bfloat16(acc3[m][n][r]);
      }
    }
}

// ---------------- SSD K2: carry propagation, in-place hend -> hinit ----------------
__global__ __launch_bounds__(256) void carry_k(
    bf16* __restrict__ hend, const float* __restrict__ sarr) {
  int blk = blockIdx.x;  // b*64 + h
  int tid = threadIdx.x;
  bf16* base = hend + (size_t)blk * NCH * 8192 + tid * 32;
  const float* sp = sarr + (size_t)blk * Ln;
  float c[32];
#pragma unroll
  for (int i = 0; i < 32; ++i) c[i] = 0.f;
  for (int j = 0; j < NCH; ++j) {
    float aT = __expf(sp[j * LC2 + LC2 - 1]);
    bf16* pj = base + (size_t)j * 8192;
    float tmp[32];
#pragma unroll
    for (int q = 0; q < 4; ++q) {
      us8 v = ((const us8*)pj)[q];
#pragma unroll
      for (int e = 0; e < 8; ++e) tmp[q * 8 + e] = bf2f(v[e]);
    }
#pragma unroll
    for (int q = 0; q < 4; ++q) {
      us8 o;
#pragma unroll
      for (int e = 0; e < 8; ++e) ((bf16*)&o)[e] = __float2bfloat16(c[q * 8 + e]);
      ((us8*)pj)[q] = o;
    }
#pragma unroll
    for (int i = 0; i < 32; ++i) c[i] = fmaf(aT, c[i], tmp[i]);
  }
}

// ---------------- SSD K3: Y += (exp(s_i)*C_i) @ Hinit^T ----------------
__global__ __launch_bounds__(256) void ssd2_k(
    const bf16* __restrict__ bc, const float* __restrict__ sarr,
    const bf16* __restrict__ hinit, bf16* __restrict__ ys) {
  __shared__ bf16 Ce[64][136];
  __shared__ bf16 Hs[64][136];
  __shared__ float sA[64];
  int idx = blockIdx.x;
  int ch = idx & (NCH - 1), h = (idx >> 5) & 63, b = idx >> 11;
  int tid = threadIdx.x;
  size_t bt0 = (size_t)b * Ln + ch * LC2;
  if (tid < 64) sA[tid] = sarr[(size_t)(b * 64 + h) * Ln + ch * LC2 + tid];
  __syncthreads();
  {
    int i = tid & 63, q = tid >> 6;
    float ei = __expf(sA[i]);
    const bf16* src = bc + (bt0 + i) * 256 + 128 + q * 32;
#pragma unroll
    for (int m8 = 0; m8 < 4; ++m8) {
      us8 v = *(const us8*)(src + m8 * 8);
      us8 o;
#pragma unroll
      for (int e = 0; e < 8; ++e) ((bf16*)&o)[e] = __float2bfloat16(bf2f(v[e]) * ei);
      *(us8*)&Ce[i][q * 32 + m8 * 8] = o;
    }
    const bf16* hsrc = hinit + ((size_t)((b * 64 + h) * NCH + ch)) * 8192 + i * 128 + q * 32;
#pragma unroll
    for (int m8 = 0; m8 < 4; ++m8)
      *(us8*)&Hs[i][q * 32 + m8 * 8] = *(const us8*)(hsrc + m8 * 8);
  }
  __syncthreads();
  int lane = tid & 63, wid = tid >> 6;
  int wr = wid >> 1, wc = wid & 1;
  int l15 = lane & 15, l4 = lane >> 4;
  f32x4 acc[2][2] = {};
#pragma unroll
  for (int kk = 0; kk < 4; ++kk) {
    int kr = kk * 32 + l4 * 8;
    bf16x8s a0 = *(const bf16x8s*)&Ce[wr * 32 + l15][kr];
    bf16x8s a1 = *(const bf16x8s*)&Ce[wr * 32 + 16 + l15][kr];
    bf16x8s b0 = *(const bf16x8s*)&Hs[wc * 32 + l15][kr];
    bf16x8s b1 = *(const bf16x8s*)&Hs[wc * 32 + 16 + l15][kr];
    acc[0][0] = MFMA16(a0, b0, acc[0][0]);
    acc[0][1] = MFMA16(a0, b1, acc[0][1]);
    acc[1][0] = MFMA16(a1, b0, acc[1][0]);
    acc[1][1] = MFMA16(a1, b1, acc[1][1]);
  }
#pragma unroll
  for (int m = 0; m < 2; ++m)
#pragma unroll
    for (int n = 0; n < 2; ++n) {
      int p = wc * 32 + n * 16 + l15;
#pragma unroll
      for (int r = 0; r < 4; ++r) {
        int i = wr * 32 + m * 16 + l4 * 4 + r;
        bf16* yy = &ys[(bt0 + i) * DINn + h * 64 + p];
        *yy = __float2bfloat16(bfload(yy) + acc[m][n][r]);
      }
    }
}

// ---------------- gated rmsnorm (+ D*x): out = rmsnorm((y + D*x) * silu(z)) * w ----------------
__global__ __launch_bounds__(256) void gated_norm_k(
    const bf16* __restrict__ ys, const bf16* __restrict__ xb,
    const float* __restrict__ Dp, const bf16* __restrict__ proj,
    const float* __restrict__ gw, bf16* __restrict__ out) {
  int row = blockIdx.x, tid = threadIdx.x;
  const bf16* yr = ys + (size_t)row * DINn;
  const bf16* xr = xb + (size_t)row * DINn;
  const bf16* zr = proj + (size_t)row * DPROJ;
  float v[2][8];
  float ss = 0.f;
#pragma unroll
  for (int it = 0; it < 2; ++it) {
    int base = (it * 256 + tid) * 8;
    float Dh = Dp[base >> 6];
    us8 y = *(const us8*)(yr + base);
    us8 x = *(const us8*)(xr + base);
    us8 z = *(const us8*)(zr + base);
#pragma unroll
    for (int j = 0; j < 8; ++j) {
      float zf = bf2f(z[j]);
      float val = (bf2f(y[j]) + Dh * bf2f(x[j])) * zf * sigmoidf_(zf);
      v[it][j] = val; ss += val * val;
    }
  }
#pragma unroll
  for (int o = 1; o < 64; o <<= 1) ss += __shfl_xor(ss, o, 64);
  __shared__ float red[4];
  if ((tid & 63) == 0) red[tid >> 6] = ss;
  __syncthreads();
  float sc = rsqrtf((red[0] + red[1] + red[2] + red[3]) / DINn + 1e-5f);
#pragma unroll
  for (int it = 0; it < 2; ++it) {
    int base = (it * 256 + tid) * 8;
    float4 g0 = *(const float4*)(gw + base);
    float4 g1 = *(const float4*)(gw + base + 4);
    float gv[8] = {g0.x, g0.y, g0.z, g0.w, g1.x, g1.y, g1.z, g1.w};
    us8 ov;
#pragma unroll
    for (int j = 0; j < 8; ++j)
      ((bf16*)&ov)[j] = __float2bfloat16(v[it][j] * sc * gv[j]);
    *(us8*)(out + (size_t)row * DINn + base) = ov;
  }
}

// ---------------- swiglu act, IN-PLACE on gu ----------------
__global__ __launch_bounds__(256) void act_k(bf16* __restrict__ gu) {
  int i = blockIdx.x * 256 + threadIdx.x;
  int row = i >> 10, g = i & 1023;
  bf16* rp = gu + (size_t)row * (2 * FFn) + g * 8;
  us8 a = *(const us8*)(rp);
  us8 bx = *(const us8*)(rp + FFn);
  us8 ov;
#pragma unroll
  for (int j = 0; j < 8; ++j) {
    float av = bf2f(a[j]), bv = bf2f(bx[j]);
    ((bf16*)&ov)[j] = __float2bfloat16(av * sigmoidf_(av) * bv);
  }
  *(us8*)rp = ov;
}

// ---------------- launch ----------------
extern "C" void kernel_launch(void* const* d_in, const int* in_sizes, int n_in,
                              void* d_out, int out_size, void* d_ws, size_t ws_size,
                              hipStream_t stream) {
  (void)in_sizes; (void)n_in; (void)out_size; (void)ws_size;
  const float* hidden  = (const float*)d_in[0];
  const float* w_in    = (const float*)d_in[1];
  const float* conv_w  = (const float*)d_in[2];
  const float* conv_b  = (const float*)d_in[3];
  const float* A_log   = (const float*)d_in[4];
  const float* D_ssm   = (const float*)d_in[5];
  const float* dt_bias = (const float*)d_in[6];
  const float* norm_w  = (const float*)d_in[7];
  const float* w_out   = (const float*)d_in[8];
  const float* ln1_w   = (const float*)d_in[9];
  const float* ln2_w   = (const float*)d_in[10];
  const float* w_gu    = (const float*)d_in[11];
  const float* w_dn    = (const float*)d_in[12];

  // ---- workspace layout, 247.5 MiB peak, liveness-checked ----
  char* ws = (char*)d_ws;
  const size_t OFF_WT   = 0;                          // 67,108,864  weight-T buffer (max: w_guT = exact)
  const size_t OFF_PROJ = 67108864ull;                // 69,730,304  proj bf16 [4096][8512]
  const size_t OFF_XB   = OFF_PROJ + 69730304ull;     // 33,554,432  conv x bf16 [4096][4096]
  const size_t OFF_BC   = OFF_XB  + 33554432ull;      //  2,097,152  conv B/C bf16 [4096][256]
  const size_t OFF_DTB  = OFF_BC  + 2097152ull;       //  1,048,576  dt fp32 [bt][64]
  const size_t OFF_LA   = OFF_DTB + 1048576ull;       //  1,048,576  log-dA fp32 [bt][64]
  const size_t OFF_SARR = OFF_LA  + 1048576ull;       //  1,048,576  chunk-cumsum fp32 [b][h][t]
  const size_t OFF_YS   = OFF_SARR + 1048576ull;      // 33,554,432  scan y bf16 [4096][4096]
  const size_t OFF_YBF  = OFF_YS  + 33554432ull;      // 33,554,432  gated-norm out bf16
  const size_t OFF_HLN  = OFF_YBF + 33554432ull;      // 16,777,216  ln out bf16 [4096][2048]
  // aliases (regions dead at write time):
  const size_t OFF_HEND = OFF_WT;                     // 67,108,864 EXACT: 128*32*8192*2; wT dead in mixer window
  const size_t OFF_GU   = OFF_PROJ;                   // 134,217,728 over proj..ys-head (dead after gated_norm)

  bf16*  wT   = (bf16*)(ws + OFF_WT);
  bf16*  proj = (bf16*)(ws + OFF_PROJ);
  bf16*  xb   = (bf16*)(ws + OFF_XB);
  bf16*  bcb  = (bf16*)(ws + OFF_BC);
  float* dtb  = (float*)(ws + OFF_DTB);
  float* la   = (float*)(ws + OFF_LA);
  float* sarr = (float*)(ws + OFF_SARR);
  bf16*  ysb  = (bf16*)(ws + OFF_YS);
  bf16*  ybf  = (bf16*)(ws + OFF_YBF);
  bf16*  hln  = (bf16*)(ws + OFF_HLN);
  bf16*  hend = (bf16*)(ws + OFF_HEND);
  bf16*  gu   = (bf16*)(ws + OFF_GU);

  float* h_out = (float*)d_out;                 // output 0: h  (fp32)
  float* resid = h_out + (size_t)BL * Hn;       // output 1: residual (fp32)

  // ---- mixer ----
  transpose_f2b_k<<<dim3(DPROJ / 32, Hn / 32), 256, 0, stream>>>(w_in, wT, Hn, DPROJ);
  hipMemsetAsync(wT + (size_t)DPROJ * Hn, 0, (size_t)(DPROJP - DPROJ) * Hn * 2, stream);
  rmsnorm_f32_k<<<BL, 256, 0, stream>>>(hidden, ln1_w, hln);
  gemm256_k<8, 0, bf16><<<(DPROJP / 256) * (BL / 256), 512, 0, stream>>>(
      hln, wT, proj, nullptr, Hn, Hn, DPROJ, DPROJP / 256);

  conv_silu_k<<<dim3(CONVD / 256, BL), 256, 0, stream>>>(proj, conv_w, conv_b, xb, bcb);
  dtda_k<<<BL * NHn / 256, 256, 0, stream>>>(proj, dt_bias, A_log, dtb, la);
  cumsum_k<<<Bn * NHn, 256, 0, stream>>>(la, sarr);

  // SSD scan (hend aliases wT)
  ssd1_k<<<Bn * NHn * NCH, 256, 0, stream>>>(xb, bcb, dtb, sarr, ysb, hend);
  carry_k<<<Bn * NHn, 256, 0, stream>>>(hend, sarr);
  ssd2_k<<<Bn * NHn * NCH, 256, 0, stream>>>(bcb, sarr, hend, ysb);

  gated_norm_k<<<BL, 256, 0, stream>>>(ysb, xb, D_ssm, proj, norm_w, ybf);
  transpose_f2b_k<<<dim3(Hn / 32, DINn / 32), 256, 0, stream>>>(w_out, wT, DINn, Hn);
  gemm256_k<4, 1, float><<<(Hn / 256) * (BL / 128), 512, 0, stream>>>(
      ybf, wT, resid, hidden, DINn, DINn, Hn, Hn / 256);

  // ---- MLP ----
  rmsnorm_f32_k<<<BL, 256, 0, stream>>>(resid, ln2_w, hln);
  transpose_f2b_k<<<dim3(2 * FFn / 32, Hn / 32), 256, 0, stream>>>(w_gu, wT, Hn, 2 * FFn);
  gemm256_k<8, 0, bf16><<<(2 * FFn / 256) * (BL / 256), 512, 0, stream>>>(
      hln, wT, gu, nullptr, Hn, Hn, 2 * FFn, 2 * FFn / 256);
  act_k<<<BL * FFn / 8 / 256, 256, 0, stream>>>(gu);
  transpose_f2b_k<<<dim3(Hn / 32, FFn / 32), 256, 0, stream>>>(w_dn, wT, FFn, Hn);
  gemm256_k<4, 0, float><<<(Hn / 256) * (BL / 128), 512, 0, stream>>>(
      gu, wT, h_out, nullptr, FFn, 2 * FFn, Hn, Hn / 256);
}